// Round 4
// baseline (271.768 us; speedup 1.0000x reference)
//
#include <hip/hip_runtime.h>

typedef _Float16 half_t;
typedef half_t h2 __attribute__((ext_vector_type(2)));
typedef half_t h4 __attribute__((ext_vector_type(4)));
typedef float f4 __attribute__((ext_vector_type(4)));

#define J 10
#define P 16384
#define D 8
#define O 16
#define B 32

#define PTILE 8
#define TILES_PER_BLK 4
#define NBLK (P / PTILE / TILES_PER_BLK)   // 512 blocks = exactly 2 per CU
#define SJO (B * J * O)                    // 5120

#define WT_PLS 2576              // bytes per pl slab: 10j*16o*8d*2B + 16 pad
#define WT_PLH (WT_PLS / 2)      // 1288 halfs
#define WT_BYTES (PTILE * WT_PLS)          // 20608
#define XS_BYTES (PTILE * B * 16)          // 4096
#define BUF_BYTES (WT_BYTES + XS_BYTES)    // 24704 per buffer
#define VL_OFF (2 * BUF_BYTES)             // 49408
#define VL_STRIDE 84             // dwords per b-row of vls (80 data + 4 pad)
#define SMEM_BYTES (VL_OFF + B * VL_STRIDE * 4)  // 60160 <= 64 KB
// epilogue s_blk aliases smem: 4*16*164*4 = 41984 B <= 60160  OK

// ---- DPP cross-lane helpers (squash kernel) ----
template <int CTRL>
__device__ __forceinline__ float dpp_mov_f(float v) {
    return __int_as_float(__builtin_amdgcn_update_dpp(
        0, __float_as_int(v), CTRL, 0xF, 0xF, true));
}
__device__ __forceinline__ float row_sum16(float v) {
    v += dpp_mov_f<0xB1>(v);   // quad_perm xor 1
    v += dpp_mov_f<0x4E>(v);   // quad_perm xor 2
    v += dpp_mov_f<0x124>(v);  // row_ror:4
    v += dpp_mov_f<0x128>(v);  // row_ror:8
    return v;
}

__device__ __forceinline__ h2 pkrtz(float a, float b) {
    return __builtin_bit_cast(h2, __builtin_amdgcn_cvt_pkrtz(a, b));
}

// cross-lane adds on the VALU pipe (permlane swaps); LDS-pipe fallback
__device__ __forceinline__ float xadd16(float v) {
#if __has_builtin(__builtin_amdgcn_permlane16_swap)
    auto r = __builtin_amdgcn_permlane16_swap(__float_as_uint(v),
                                              __float_as_uint(v), false, false);
    return __uint_as_float(r[0]) + __uint_as_float(r[1]);
#else
    return v + __shfl_xor(v, 16, 64);
#endif
}
__device__ __forceinline__ float xadd32(float v) {
#if __has_builtin(__builtin_amdgcn_permlane32_swap)
    auto r = __builtin_amdgcn_permlane32_swap(__float_as_uint(v),
                                              __float_as_uint(v), false, false);
    return __uint_as_float(r[0]) + __uint_as_float(r[1]);
#else
    return v + __shfl_xor(v, 32, 64);
#endif
}

union U4H { uint4 u; h2 h[4]; };
union U2H { uint2 u2; h2 h[2]; h4 v; };
union U1H { unsigned u; h2 h; };

// One routing pass. 512 persistent-ish blocks x 512 threads; block = four
// consecutive 8-p tiles, all 32 b, double-buffered LDS staging (T14: issue
// next tile's global loads BEFORE compute, convert+ds_write AFTER compute so
// HBM latency hides under MFMA/softmax). Round-2 profile showed all pipes
// <15% busy -> phase serialization was the bound, not any pipe.
__global__ __launch_bounds__(512, 4) void caps_pass(
    const float* __restrict__ x, const float* __restrict__ W,
    const unsigned* __restrict__ vh, float* __restrict__ s_acc, int first)
{
    __shared__ char smem[SMEM_BYTES];
    unsigned* vls = (unsigned*)(smem + VL_OFF);
    float* s_blk = (float*)smem;   // aliased after compute

    const int tid = threadIdx.x;
    const int tile0 = blockIdx.x * TILES_PER_BLK;

    // staging decode: W stager = (jh:2, pl:8, d:8, o4:4), x stager = (hf:2, bl:32, pl:8)
    const int w_o4 = tid & 3, w_d = (tid >> 2) & 7, w_pl = (tid >> 5) & 7;
    const int w_jh = tid >> 8;
    const int x_pl = tid & 7, x_bl = (tid >> 3) & 31, x_hf = tid >> 8;

    // ---- stage Vsum fp16 once: vh [b][j][8dw] -> vls [b][j*8+dw], stride 84 ----
    if (!first && tid < B * J) {
        const int b = tid / J, j = tid - b * J;
        const uint4* s = (const uint4*)(vh + (size_t)tid * 8);
        uint4* dvl = (uint4*)(vls + b * VL_STRIDE + j * 8);
        dvl[0] = s[0];
        dvl[1] = s[1];
    }

    // in-flight staging registers (24 VGPR)
    float4 wf0, wf1, wf2, wf3, wf4;
    float4 xf;

#define LOADT(t)                                                               \
    {                                                                          \
        const int p0 = (tile0 + (t)) * PTILE;                                  \
        const float* wsrc = W + (size_t)(p0 + w_pl) * 128 + w_d * 16 + w_o4 * 4; \
        const size_t jstep = (size_t)P * 128;                                  \
        const float* wj = wsrc + (size_t)(w_jh * 5) * jstep;                   \
        wf0 = *(const float4*)(wj);                                            \
        wf1 = *(const float4*)(wj + jstep);                                    \
        wf2 = *(const float4*)(wj + 2 * jstep);                                \
        wf3 = *(const float4*)(wj + 3 * jstep);                                \
        wf4 = *(const float4*)(wj + 4 * jstep);                                \
        xf = *(const float4*)(x + ((size_t)x_bl * P + p0 + x_pl) * D + x_hf * 4); \
    }

#define WRITET(k)                                                              \
    {                                                                          \
        half_t* Wtw = (half_t*)(smem + (k) * BUF_BYTES);                       \
        half_t* xsw = (half_t*)(smem + (k) * BUF_BYTES + WT_BYTES);            \
        half_t* dst = Wtw + w_pl * WT_PLH + (w_o4 * 4) * 8 + w_d;              \
        half_t* dj = dst + (w_jh * 5) * 128;                                   \
        dj[0] = (half_t)wf0.x; dj[8] = (half_t)wf0.y;                          \
        dj[16] = (half_t)wf0.z; dj[24] = (half_t)wf0.w;                        \
        dj += 128;                                                             \
        dj[0] = (half_t)wf1.x; dj[8] = (half_t)wf1.y;                          \
        dj[16] = (half_t)wf1.z; dj[24] = (half_t)wf1.w;                        \
        dj += 128;                                                             \
        dj[0] = (half_t)wf2.x; dj[8] = (half_t)wf2.y;                          \
        dj[16] = (half_t)wf2.z; dj[24] = (half_t)wf2.w;                        \
        dj += 128;                                                             \
        dj[0] = (half_t)wf3.x; dj[8] = (half_t)wf3.y;                          \
        dj[16] = (half_t)wf3.z; dj[24] = (half_t)wf3.w;                        \
        dj += 128;                                                             \
        dj[0] = (half_t)wf4.x; dj[8] = (half_t)wf4.y;                          \
        dj[16] = (half_t)wf4.z; dj[24] = (half_t)wf4.w;                        \
        U2H pk;                                                                \
        pk.h[0] = pkrtz(xf.x, xf.y);                                           \
        pk.h[1] = pkrtz(xf.z, xf.w);                                           \
        *(uint2*)(xsw + ((size_t)x_pl * 32 + x_bl) * 8 + x_hf * 4) = pk.u2;    \
    }

    const int lane = tid & 63;
    const int wv   = tid >> 6;        // 0..7
    const int bh   = wv >> 2;         // batch half (0/1)
    const int wid2 = wv & 3;          // pl group (2 pl each)
    const int bl16 = lane & 15;       // b within half; also o-row for A-frag
    const int q    = lane >> 4;       // k-group / o-reg group
    const unsigned kmask = (q < 2) ? 0xFFFFFFFFu : 0u;  // zero x for k>=8
    const int vbase = (bh * 16 + bl16) * VL_STRIDE + q * 2;

    f4 acc[J];
#pragma unroll
    for (int j = 0; j < J; ++j) acc[j] = (f4){0.f, 0.f, 0.f, 0.f};
    const f4 zf = (f4){0.f, 0.f, 0.f, 0.f};

    // prologue: stage tile 0 into buffer 0
    LOADT(0);
    WRITET(0);
    __syncthreads();

#pragma unroll 1
    for (int t = 0; t < TILES_PER_BLK; ++t) {
        const int cur = t & 1;
        if (t + 1 < TILES_PER_BLK) LOADT(t + 1);   // issue early (T14)

        const half_t* Wt = (const half_t*)(smem + cur * BUF_BYTES);
        const half_t* xs = (const half_t*)(smem + cur * BUF_BYTES + WT_BYTES);

#pragma unroll 1
        for (int pi = 0; pi < 2; ++pi) {
            const int pl = wid2 * 2 + pi;

            // B operand: x fragment, k>=8 zeroed
            U2H xv;
            xv.u2 = *(const uint2*)(xs + (size_t)(pl * 32 + bh * 16 + bl16) * 8
                                    + 4 * (q & 1));
            xv.u2.x &= kmask;
            xv.u2.y &= kmask;
            const h4 bfrag = xv.v;

            const half_t* wbase = Wt + pl * WT_PLH + bl16 * 8 + 4 * (q & 1);

            h2 uh[J][2];
            float lg[J];
#pragma unroll
            for (int j = 0; j < J; ++j) {
                const h4 af = *(const h4*)(wbase + j * 128);  // A = W^T row o=bl16
                f4 u = __builtin_amdgcn_mfma_f32_16x16x16f16(af, bfrag, zf, 0, 0, 0);
                if (first) {
#pragma unroll
                    for (int r = 0; r < 4; ++r)
                        acc[j][r] = fmaf(0.1f, u[r], acc[j][r]);
                } else {
                    uh[j][0] = pkrtz(u[0], u[1]);
                    uh[j][1] = pkrtz(u[2], u[3]);
                    U2H vf;
                    vf.u2 = *(const uint2*)(vls + vbase + j * 8);
                    lg[j] = __builtin_amdgcn_fdot2(uh[j][1], vf.h[1],
                            __builtin_amdgcn_fdot2(uh[j][0], vf.h[0], 0.f, false),
                            false);
                }
            }

            if (!first) {
#pragma unroll
                for (int j = 0; j < J; ++j) lg[j] = xadd16(lg[j]);
#pragma unroll
                for (int j = 0; j < J; ++j) lg[j] = xadd32(lg[j]);
                // max-free softmax: |lg| <~ 35 -> exp safe in fp32
                float e[J], Z = 0.f;
#pragma unroll
                for (int j = 0; j < J; ++j) { e[j] = __expf(lg[j]); Z += e[j]; }
                const float rZ = __builtin_amdgcn_rcpf(Z);
#pragma unroll
                for (int j = 0; j < J; ++j) {
                    const float c = e[j] * rZ;
                    acc[j][0] = fmaf(c, (float)uh[j][0][0], acc[j][0]);
                    acc[j][1] = fmaf(c, (float)uh[j][0][1], acc[j][1]);
                    acc[j][2] = fmaf(c, (float)uh[j][1][0], acc[j][2]);
                    acc[j][3] = fmaf(c, (float)uh[j][1][1], acc[j][3]);
                }
            }
        }

        if (t + 1 < TILES_PER_BLK) WRITET(cur ^ 1);  // write late (T14)
        __syncthreads();
    }

    // ---- epilogue: per-wave partials -> LDS (aliases buffers) -> atomics ----
    // two rounds (bh=0 then bh=1), s_blk = [wid2][bl][164]
#pragma unroll 1
    for (int r = 0; r < 2; ++r) {
        if (bh == r) {
#pragma unroll
            for (int j = 0; j < J; ++j)
                *(f4*)&s_blk[(size_t)(wid2 * 16 + bl16) * 164 + j * 16 + 4 * q]
                    = acc[j];
        }
        __syncthreads();
        for (int t = tid; t < 16 * 160; t += 512) {
            const int bl = t / 160, rr = t - bl * 160;
            const float v = s_blk[bl * 164 + rr] + s_blk[(16 + bl) * 164 + rr]
                          + s_blk[(32 + bl) * 164 + rr] + s_blk[(48 + bl) * 164 + rr];
            atomicAdd(&s_acc[(size_t)(r * 16 + bl) * 160 + rr], v);
        }
        __syncthreads();
    }
}

// v = squash(s); Vsum += v; emit vh (fp16 o-pairs, layout [b][j][o/2]);
// zero s_acc; optionally emit v. One block per b: lane=(o:16, j:16), j<10 active.
__global__ __launch_bounds__(256) void caps_squash(
    float* __restrict__ s_acc, float* __restrict__ Vsum,
    unsigned* __restrict__ vh, float* __restrict__ out, int write_out)
{
    const int b = blockIdx.x;
    const int o = threadIdx.x & 15;
    const int j = threadIdx.x >> 4;
    const bool act = j < J;
    const int idx = (b * J + (act ? j : 0)) * O + o;
    float s = act ? s_acc[idx] : 0.f;
    const float sq = row_sum16(s * s);
    float vnew = 0.f;
    if (act) {
        const float scale = sqrtf(sq) / (1.f + sq);   // |s|^2/((1+|s|^2)|s|)
        const float v = s * scale;
        vnew = Vsum[idx] + v;
        Vsum[idx] = vnew;
        s_acc[idx] = 0.f;
        if (write_out) out[idx] = v;
    }
    const float vpart = __shfl_xor(vnew, 1, 64);      // partner o^1
    if (act && !(o & 1)) {
        U1H t; t.h = pkrtz(vnew, vpart);
        vh[(size_t)(b * J + j) * 8 + (o >> 1)] = t.u;
    }
}

__global__ __launch_bounds__(256) void caps_zero(float* __restrict__ ws)
{
    const int i = blockIdx.x * 256 + threadIdx.x;
    if (i < 2 * SJO) ws[i] = 0.f;   // s_acc + Vsum
}

extern "C" void kernel_launch(void* const* d_in, const int* in_sizes, int n_in,
                              void* d_out, int out_size, void* d_ws, size_t ws_size,
                              hipStream_t stream)
{
    const float* x = (const float*)d_in[0];
    const float* W = (const float*)d_in[1];
    float* out = (float*)d_out;

    float* s_acc = (float*)d_ws;               // SJO floats
    float* Vsum  = s_acc + SJO;                // SJO floats
    unsigned* vh = (unsigned*)(Vsum + SJO);    // B*J*8 dwords (10 KB)

    caps_zero<<<dim3(40), 256, 0, stream>>>(s_acc);

    for (int it = 0; it < 3; ++it) {
        caps_pass<<<dim3(NBLK), 512, 0, stream>>>(x, W, vh, s_acc, it == 0 ? 1 : 0);
        caps_squash<<<dim3(B), 256, 0, stream>>>(s_acc, Vsum, vh, out, it == 2 ? 1 : 0);
    }
}

// Round 5
// 238.920 us; speedup vs baseline: 1.1375x; 1.1375x over previous
//
#include <hip/hip_runtime.h>

typedef _Float16 half_t;
typedef half_t h2 __attribute__((ext_vector_type(2)));
typedef half_t h4 __attribute__((ext_vector_type(4)));
typedef float f4 __attribute__((ext_vector_type(4)));

#define J 10
#define P 16384
#define D 8
#define O 16
#define B 32

#define SJO (B * J * O)          // 5120
#define VL_STRIDE 84             // dwords per b-row of vls (80 data + 4 pad)

// ---- new-path geometry ----
#define PBLK 32                  // p per block (4 plg-waves x 8)
#define NBLK (P / PBLK)          // 512 blocks

// ---- workspace layout (new path) ----
#define WS_VSUM 0
#define WS_VH 20480u
#define WS_WH 32768u                               // W_h: P*J*128 halfs = 41943040 B
#define WS_XT (WS_WH + 41943040u)                  // x_t: P*B*8 halfs = 8388608 B
#define WS_PART (WS_XT + 8388608u)                 // partial: NBLK*B*J*O*4 = 10485760 B
#define WS_NEED (WS_PART + 10485760u)              // 60850176 B ~= 61 MB

// ---- DPP cross-lane helpers ----
template <int CTRL>
__device__ __forceinline__ float dpp_mov_f(float v) {
    return __int_as_float(__builtin_amdgcn_update_dpp(
        0, __float_as_int(v), CTRL, 0xF, 0xF, true));
}
__device__ __forceinline__ float row_sum16(float v) {
    v += dpp_mov_f<0xB1>(v);   // quad_perm xor 1
    v += dpp_mov_f<0x4E>(v);   // quad_perm xor 2
    v += dpp_mov_f<0x124>(v);  // row_ror:4
    v += dpp_mov_f<0x128>(v);  // row_ror:8
    return v;
}

__device__ __forceinline__ h2 pkrtz(float a, float b) {
    return __builtin_bit_cast(h2, __builtin_amdgcn_cvt_pkrtz(a, b));
}

// cross-lane adds on the VALU pipe (permlane swaps); LDS-pipe fallback
__device__ __forceinline__ float xadd16(float v) {
#if __has_builtin(__builtin_amdgcn_permlane16_swap)
    auto r = __builtin_amdgcn_permlane16_swap(__float_as_uint(v),
                                              __float_as_uint(v), false, false);
    return __uint_as_float(r[0]) + __uint_as_float(r[1]);
#else
    return v + __shfl_xor(v, 16, 64);
#endif
}
__device__ __forceinline__ float xadd32(float v) {
#if __has_builtin(__builtin_amdgcn_permlane32_swap)
    auto r = __builtin_amdgcn_permlane32_swap(__float_as_uint(v),
                                              __float_as_uint(v), false, false);
    return __uint_as_float(r[0]) + __uint_as_float(r[1]);
#else
    return v + __shfl_xor(v, 32, 64);
#endif
}

union U4H { uint4 u; h2 h[4]; };
union U2H { uint2 u2; h2 h[2]; h4 v; };
union U1H { unsigned u; h2 h; };

// ============================================================================
// Pre-pass: W fp32 [j][p][d][o] -> W_h fp16 [p][j][o][d] (MFMA A-frag layout).
// Block = 8 p, all j; LDS transpose so both global read and write are coalesced.
// ============================================================================
__global__ __launch_bounds__(256) void wconv(
    const float* __restrict__ W, half_t* __restrict__ Wh)
{
    __shared__ float ls[J][8][132];   // +4 pad: gather lanes hit distinct banks
    const int t = threadIdx.x;
    const int p0 = blockIdx.x * 8;

    // stage: 10 j * 8 p * 128 floats = 2560 float4, coalesced
#pragma unroll
    for (int it = 0; it < 10; ++it) {
        const int idx = it * 256 + t;
        const int f4i = idx & 31, pp = (idx >> 5) & 7, j = idx >> 8;
        float4 f = *(const float4*)(W + ((size_t)j * P + p0 + pp) * 128 + f4i * 4);
        *(float4*)&ls[j][pp][f4i * 4] = f;
    }
    __syncthreads();
    // write: tasks (j, pp, o) = 1280; lane o fastest -> 256B-contiguous stores
#pragma unroll
    for (int it = 0; it < 5; ++it) {
        const int idx = it * 256 + t;
        const int o = idx & 15, pp = (idx >> 4) & 7, j = idx >> 7;
        U4H pk;
#pragma unroll
        for (int dq = 0; dq < 4; ++dq)
            pk.h[dq] = pkrtz(ls[j][pp][(2 * dq) * 16 + o],
                             ls[j][pp][(2 * dq + 1) * 16 + o]);
        *(uint4*)(Wh + (((size_t)(p0 + pp) * J + j) * 16 + o) * 8) = pk.u;
    }
}

// ============================================================================
// Pre-pass: x fp32 [b][p][d] -> x_t fp16 [p][b][d]. Block = 64 p x 32 b.
// ============================================================================
__global__ __launch_bounds__(256) void xconv(
    const float* __restrict__ x, half_t* __restrict__ xt)
{
    __shared__ uint4 xls[64][33];     // +1 pad entry per row
    const int t = threadIdx.x;
    const int p0 = blockIdx.x * 64;

#pragma unroll
    for (int it = 0; it < 8; ++it) {
        const int idx = it * 256 + t;
        const int pp = idx & 63, b = idx >> 6;
        const float4* xp = (const float4*)(x + ((size_t)b * P + p0 + pp) * 8);
        float4 a = xp[0], c = xp[1];
        U4H pk;
        pk.h[0] = pkrtz(a.x, a.y);
        pk.h[1] = pkrtz(a.z, a.w);
        pk.h[2] = pkrtz(c.x, c.y);
        pk.h[3] = pkrtz(c.z, c.w);
        xls[pp][b] = pk.u;
    }
    __syncthreads();
#pragma unroll
    for (int it = 0; it < 8; ++it) {
        const int idx = it * 256 + t;
        const int b = idx & 31, pp = idx >> 5;
        *(uint4*)(xt + ((size_t)(p0 + pp) * 32 + b) * 8) = xls[pp][b];
    }
}

// ============================================================================
// Main pass (new path). 512 blocks x 512 thr; block = 32 p, all 32 b.
// NO staging: A/B fragments loaded straight from pre-converted global (L1-
// shared across the bh-pair waves). No barriers in the main loop. Partials
// to workspace (plain stores) instead of contended atomics.
// ============================================================================
__global__ __launch_bounds__(512, 4) void caps_pass(
    const half_t* __restrict__ Wh, const half_t* __restrict__ xt,
    const unsigned* __restrict__ vh, float* __restrict__ partial, int first)
{
    __shared__ float s_blk[4 * 16 * 164];        // 41984 B epilogue reduce
    __shared__ unsigned vls[B * VL_STRIDE];      // 10752 B Vsum fp16

    const int tid = threadIdx.x;
    const int p0 = blockIdx.x * PBLK;

    // stage Vsum fp16 once: vh [b][j][8dw] -> vls [b][j*8+dw]
    if (!first && tid < B * J) {
        const int b = tid / J, j = tid - b * J;
        const uint4* s = (const uint4*)(vh + (size_t)tid * 8);
        uint4* dvl = (uint4*)(vls + b * VL_STRIDE + j * 8);
        dvl[0] = s[0];
        dvl[1] = s[1];
    }

    const int lane = tid & 63;
    const int wv   = tid >> 6;        // 0..7
    const int bh   = wv >> 2;         // batch half
    const int plg  = wv & 3;          // p-group (8 p each)
    const int bl16 = lane & 15;       // b within half; also o-row for A-frag
    const int q    = lane >> 4;       // k-quad / o-reg group
    const unsigned kmask = (q < 2) ? 0xFFFFFFFFu : 0u;  // zero x for k>=8
    const int vbase = (bh * 16 + bl16) * VL_STRIDE + q * 2;

    __syncthreads();

    f4 acc[J];
#pragma unroll
    for (int j = 0; j < J; ++j) acc[j] = (f4){0.f, 0.f, 0.f, 0.f};
    const f4 zf = (f4){0.f, 0.f, 0.f, 0.f};

    const int pbase = p0 + plg * 8;
#pragma unroll 1
    for (int i = 0; i < 8; ++i) {
        const int p = pbase + i;
        const half_t* wp = Wh + ((size_t)p * J) * 128 + bl16 * 8 + (q & 1) * 4;

        U2H xv;
        xv.u2 = *(const uint2*)(xt + ((size_t)p * 32 + bh * 16 + bl16) * 8
                                + (q & 1) * 4);
        xv.u2.x &= kmask;
        xv.u2.y &= kmask;
        const h4 bfrag = xv.v;

        if (first) {
#pragma unroll
            for (int j = 0; j < J; ++j) {
                const h4 af = *(const h4*)(wp + j * 128);
                f4 u = __builtin_amdgcn_mfma_f32_16x16x16f16(af, bfrag, zf, 0, 0, 0);
#pragma unroll
                for (int r = 0; r < 4; ++r)
                    acc[j][r] = fmaf(0.1f, u[r], acc[j][r]);
            }
        } else {
            h2 uh[J][2];
            float lg[J];
#pragma unroll
            for (int j = 0; j < J; ++j) {
                const h4 af = *(const h4*)(wp + j * 128);
                f4 u = __builtin_amdgcn_mfma_f32_16x16x16f16(af, bfrag, zf, 0, 0, 0);
                uh[j][0] = pkrtz(u[0], u[1]);
                uh[j][1] = pkrtz(u[2], u[3]);
                U2H vf;
                vf.u2 = *(const uint2*)(vls + vbase + j * 8);
                lg[j] = __builtin_amdgcn_fdot2(uh[j][1], vf.h[1],
                        __builtin_amdgcn_fdot2(uh[j][0], vf.h[0], 0.f, false),
                        false);
            }
#pragma unroll
            for (int j = 0; j < J; ++j) lg[j] = xadd16(lg[j]);
#pragma unroll
            for (int j = 0; j < J; ++j) lg[j] = xadd32(lg[j]);
            // max-free softmax: |lg| <~ 35 -> exp safe in fp32
            float Z = 0.f;
#pragma unroll
            for (int j = 0; j < J; ++j) { lg[j] = __expf(lg[j]); Z += lg[j]; }
            const float rZ = __builtin_amdgcn_rcpf(Z);
#pragma unroll
            for (int j = 0; j < J; ++j) {
                const float c = lg[j] * rZ;
                acc[j][0] = fmaf(c, (float)uh[j][0][0], acc[j][0]);
                acc[j][1] = fmaf(c, (float)uh[j][0][1], acc[j][1]);
                acc[j][2] = fmaf(c, (float)uh[j][1][0], acc[j][2]);
                acc[j][3] = fmaf(c, (float)uh[j][1][1], acc[j][3]);
            }
        }
    }

    // ---- epilogue: per-wave partials -> LDS reduce -> plain stores ----
    __syncthreads();
#pragma unroll 1
    for (int r = 0; r < 2; ++r) {
        if (bh == r) {
#pragma unroll
            for (int j = 0; j < J; ++j)
                *(f4*)&s_blk[(size_t)(plg * 16 + bl16) * 164 + j * 16 + 4 * q]
                    = acc[j];
        }
        __syncthreads();
        for (int t = tid; t < 16 * 160; t += 512) {
            const int bl = t / 160, rr = t - bl * 160;
            const float v = s_blk[bl * 164 + rr] + s_blk[(16 + bl) * 164 + rr]
                          + s_blk[(32 + bl) * 164 + rr] + s_blk[(48 + bl) * 164 + rr];
            partial[((size_t)blockIdx.x * 32 + r * 16 + bl) * 160 + rr] = v;
        }
        __syncthreads();
    }
}

// ============================================================================
// Squash (new path): reduce 512 partial rows, squash, update Vsum, emit vh.
// 32 blocks (one per b) x 1024 thr: (o:16, j:16, hf:4); hf quarters of blocks.
// ============================================================================
__global__ __launch_bounds__(1024) void caps_squash(
    const float* __restrict__ partial, float* __restrict__ Vsum,
    unsigned* __restrict__ vh, float* __restrict__ out, int write_out)
{
    __shared__ float red[4][160];
    const int b = blockIdx.x;
    const int t = threadIdx.x;
    const int o = t & 15, j = (t >> 4) & 15, hf = t >> 8;
    const bool act = j < J;
    const int jo = j * 16 + o;

    if (act) {
        float s = 0.f;
        const float* pp = partial + (size_t)hf * 128 * (32 * 160) + b * 160 + jo;
#pragma unroll 8
        for (int k = 0; k < 128; ++k) s += pp[(size_t)k * (32 * 160)];
        red[hf][jo] = s;
    }
    __syncthreads();
    if (hf == 0) {
        const float s = act ? red[0][jo] + red[1][jo] + red[2][jo] + red[3][jo]
                            : 0.f;
        const float sq = row_sum16(s * s);
        float vnew = 0.f;
        const int idx = (b * J + (act ? j : 0)) * O + o;
        if (act) {
            const float scale = sqrtf(sq) / (1.f + sq);  // |s|^2/((1+|s|^2)|s|)
            const float v = s * scale;
            vnew = Vsum[idx] + v;
            Vsum[idx] = vnew;
            if (write_out) out[idx] = v;
        }
        const float vpart = __shfl_xor(vnew, 1, 64);     // partner o^1
        if (act && !(o & 1)) {
            U1H tt; tt.h = pkrtz(vnew, vpart);
            vh[(size_t)(b * J + j) * 8 + (o >> 1)] = tt.u;
        }
    }
}

__global__ __launch_bounds__(256) void caps_zero(float* __restrict__ ws, int n)
{
    const int i = blockIdx.x * 256 + threadIdx.x;
    if (i < n) ws[i] = 0.f;
}

// ============================================================================
// Fallback path (round-2 verified kernels, 250 us) if ws_size < WS_NEED.
// ============================================================================
#define FB_PTILE 16
#define FB_NB (P / FB_PTILE)
#define FB_WT_PLS 2576
#define FB_WT_PLH (FB_WT_PLS / 2)
#define FB_XS_OFF (FB_PTILE * FB_WT_PLS)
#define FB_VL_OFF (FB_XS_OFF + FB_PTILE * B * 16)
#define FB_SMEM (FB_VL_OFF + B * VL_STRIDE * 4)

__global__ __launch_bounds__(512, 4) void caps_pass_fb(
    const float* __restrict__ x, const float* __restrict__ W,
    const unsigned* __restrict__ vh, float* __restrict__ s_acc, int first)
{
    __shared__ char smem[FB_SMEM];
    half_t* Wt = (half_t*)smem;
    half_t* xs = (half_t*)(smem + FB_XS_OFF);
    unsigned* vls = (unsigned*)(smem + FB_VL_OFF);
    float* s_blk = (float*)smem;

    const int tid = threadIdx.x;
    const int p0 = blockIdx.x * FB_PTILE;

    {
        const int o4 = tid & 3, d = (tid >> 2) & 7, pl = tid >> 5;
        const float* src = W + (size_t)p0 * (D * O) + (size_t)tid * 4;
        half_t* dst = Wt + pl * FB_WT_PLH + (o4 * 4) * 8 + d;
#pragma unroll
        for (int j = 0; j < J; ++j) {
            float4 f = *(const float4*)(src + (size_t)j * P * (D * O));
            half_t* dj = dst + j * 128;
            dj[0]  = (half_t)f.x;
            dj[8]  = (half_t)f.y;
            dj[16] = (half_t)f.z;
            dj[24] = (half_t)f.w;
        }
    }
    {
        const int bl = tid >> 4, pl = tid & 15;
        const float4* xp = (const float4*)(x + ((size_t)bl * P + p0 + pl) * D);
        float4 a = xp[0], c = xp[1];
        U4H pk;
        pk.h[0] = pkrtz(a.x, a.y);
        pk.h[1] = pkrtz(a.z, a.w);
        pk.h[2] = pkrtz(c.x, c.y);
        pk.h[3] = pkrtz(c.z, c.w);
        *(uint4*)(xs + (size_t)(pl * 16 + bl) * 8) = pk.u;
    }
    if (!first && tid < B * J) {
        const int b = tid / J, j = tid - b * J;
        const uint4* s = (const uint4*)(vh + (size_t)tid * 8);
        uint4* dvl = (uint4*)(vls + b * VL_STRIDE + j * 8);
        dvl[0] = s[0];
        dvl[1] = s[1];
    }

    const int lane = tid & 63;
    const int wv   = tid >> 6;
    const int bh   = wv >> 2;
    const int wid2 = wv & 3;
    const int bl16 = lane & 15;
    const int q    = lane >> 4;
    const unsigned kmask = (q < 2) ? 0xFFFFFFFFu : 0u;
    const int vbase = (bh * 16 + bl16) * VL_STRIDE + q * 2;

    __syncthreads();

    f4 acc[J];
#pragma unroll
    for (int j = 0; j < J; ++j) acc[j] = (f4){0.f, 0.f, 0.f, 0.f};
    const f4 zf = (f4){0.f, 0.f, 0.f, 0.f};

#pragma unroll 1
    for (int pi = 0; pi < 4; ++pi) {
        const int pl = wid2 * 4 + pi;
        U2H xv;
        xv.u2 = *(const uint2*)(xs + (size_t)(pl * 16 + bl16) * 8 + 4 * (q & 1));
        xv.u2.x &= kmask;
        xv.u2.y &= kmask;
        const h4 bfrag = xv.v;
        const half_t* wbase = Wt + pl * FB_WT_PLH + bl16 * 8 + 4 * (q & 1);

        h2 uh[J][2];
        float lg[J];
#pragma unroll
        for (int j = 0; j < J; ++j) {
            const h4 af = *(const h4*)(wbase + j * 128);
            f4 u = __builtin_amdgcn_mfma_f32_16x16x16f16(af, bfrag, zf, 0, 0, 0);
            if (first) {
#pragma unroll
                for (int r = 0; r < 4; ++r)
                    acc[j][r] = fmaf(0.1f, u[r], acc[j][r]);
            } else {
                uh[j][0] = pkrtz(u[0], u[1]);
                uh[j][1] = pkrtz(u[2], u[3]);
                U2H vf;
                vf.u2 = *(const uint2*)(vls + vbase + j * 8);
                lg[j] = __builtin_amdgcn_fdot2(uh[j][1], vf.h[1],
                        __builtin_amdgcn_fdot2(uh[j][0], vf.h[0], 0.f, false),
                        false);
            }
        }
        if (!first) {
#pragma unroll
            for (int j = 0; j < J; ++j) lg[j] = xadd16(lg[j]);
#pragma unroll
            for (int j = 0; j < J; ++j) lg[j] = xadd32(lg[j]);
            float e[J], Z = 0.f;
#pragma unroll
            for (int j = 0; j < J; ++j) { e[j] = __expf(lg[j]); Z += e[j]; }
            const float rZ = __builtin_amdgcn_rcpf(Z);
#pragma unroll
            for (int j = 0; j < J; ++j) {
                const float c = e[j] * rZ;
                acc[j][0] = fmaf(c, (float)uh[j][0][0], acc[j][0]);
                acc[j][1] = fmaf(c, (float)uh[j][0][1], acc[j][1]);
                acc[j][2] = fmaf(c, (float)uh[j][1][0], acc[j][2]);
                acc[j][3] = fmaf(c, (float)uh[j][1][1], acc[j][3]);
            }
        }
    }

    __syncthreads();
#pragma unroll 1
    for (int r = 0; r < 2; ++r) {
        if (bh == r) {
#pragma unroll
            for (int j = 0; j < J; ++j)
                *(f4*)&s_blk[(size_t)(wid2 * 16 + bl16) * 164 + j * 16 + 4 * q]
                    = acc[j];
        }
        __syncthreads();
        for (int t = tid; t < 16 * 160; t += 512) {
            const int bl = t / 160, rr = t - bl * 160;
            const float v = s_blk[bl * 164 + rr] + s_blk[(16 + bl) * 164 + rr]
                          + s_blk[(32 + bl) * 164 + rr] + s_blk[(48 + bl) * 164 + rr];
            atomicAdd(&s_acc[(size_t)(r * 16 + bl) * 160 + rr], v);
        }
        __syncthreads();
    }
}

__global__ __launch_bounds__(256) void caps_squash_fb(
    float* __restrict__ s_acc, float* __restrict__ Vsum,
    unsigned* __restrict__ vh, float* __restrict__ out, int write_out)
{
    const int b = blockIdx.x;
    const int o = threadIdx.x & 15;
    const int j = threadIdx.x >> 4;
    const bool act = j < J;
    const int idx = (b * J + (act ? j : 0)) * O + o;
    float s = act ? s_acc[idx] : 0.f;
    const float sq = row_sum16(s * s);
    float vnew = 0.f;
    if (act) {
        const float scale = sqrtf(sq) / (1.f + sq);
        const float v = s * scale;
        vnew = Vsum[idx] + v;
        Vsum[idx] = vnew;
        s_acc[idx] = 0.f;
        if (write_out) out[idx] = v;
    }
    const float vpart = __shfl_xor(vnew, 1, 64);
    if (act && !(o & 1)) {
        U1H t; t.h = pkrtz(vnew, vpart);
        vh[(size_t)(b * J + j) * 8 + (o >> 1)] = t.u;
    }
}

extern "C" void kernel_launch(void* const* d_in, const int* in_sizes, int n_in,
                              void* d_out, int out_size, void* d_ws, size_t ws_size,
                              hipStream_t stream)
{
    const float* x = (const float*)d_in[0];
    const float* W = (const float*)d_in[1];
    float* out = (float*)d_out;
    char* ws = (char*)d_ws;

    if (ws_size >= WS_NEED) {
        float* Vsum = (float*)(ws + WS_VSUM);
        unsigned* vh = (unsigned*)(ws + WS_VH);
        half_t* Wh = (half_t*)(ws + WS_WH);
        half_t* xt = (half_t*)(ws + WS_XT);
        float* partial = (float*)(ws + WS_PART);

        caps_zero<<<dim3(20), 256, 0, stream>>>(Vsum, SJO);
        wconv<<<dim3(P / 8), 256, 0, stream>>>(W, Wh);
        xconv<<<dim3(P / 64), 256, 0, stream>>>(x, xt);

        for (int it = 0; it < 3; ++it) {
            caps_pass<<<dim3(NBLK), 512, 0, stream>>>(Wh, xt, vh, partial,
                                                      it == 0 ? 1 : 0);
            caps_squash<<<dim3(B), 1024, 0, stream>>>(partial, Vsum, vh, out,
                                                      it == 2 ? 1 : 0);
        }
    } else {
        float* s_acc = (float*)d_ws;
        float* Vsum  = s_acc + SJO;
        unsigned* vh = (unsigned*)(Vsum + SJO);

        caps_zero<<<dim3(40), 256, 0, stream>>>(s_acc, 2 * SJO);
        for (int it = 0; it < 3; ++it) {
            caps_pass_fb<<<dim3(FB_NB), 512, 0, stream>>>(x, W, vh, s_acc,
                                                          it == 0 ? 1 : 0);
            caps_squash_fb<<<dim3(B), 256, 0, stream>>>(s_acc, Vsum, vh, out,
                                                        it == 2 ? 1 : 0);
        }
    }
}